// Round 7
// baseline (26.130 us; speedup 1.0000x reference)
//
#include <hip/hip_runtime.h>
#include <hip/hip_bf16.h>

// Problem constants (match reference)
#define BB 32
#define VV 4
#define JJ 17
#define HH 128
#define WW 128

constexpr int   SLICE   = HH * WW;            // 16384 floats per (b,v,j)
constexpr int   NSLICE  = BB * VV * JJ;       // 2176 slices
constexpr int   NBLK    = NSLICE * 2;         // 4352 half-slice blocks
constexpr long long NTOT = (long long)NSLICE * SLICE; // 35,651,584
constexpr float INV_NTOT = 1.0f / (float)NTOT;

// Native clang vector for __builtin_nontemporal_load (HIP_vector_type invalid there)
typedef float f32x4 __attribute__((ext_vector_type(4)));

// Kernel 1: one block per HALF-slice (4352 blocks = exactly 17 per CU).
// No LDS, no barrier: each thread computes its 4 ex + 8 ey gaussian factors
// in registers (12 __expf), then streams 8 nt float4 loads of pred.
// gt = ey[h]*ex[w]; partial = sum (pred - gt)^2, pre-scaled by 1/NTOT.
__global__ __launch_bounds__(256)
void heatmap_mse_partial(const float* __restrict__ pred,
                         const float* __restrict__ proj,    // [B,V,3,4]
                         const float* __restrict__ joints,  // [B,J,3]
                         float* __restrict__ partials)      // [NBLK]
{
    const int blk  = blockIdx.x;
    const int bvj  = blk >> 1;        // slice index
    const int half = blk & 1;         // 0: rows 0..63, 1: rows 64..127
    const int b  = bvj / (VV * JJ);
    const int vj = bvj - b * (VV * JJ);
    const int v  = vj / JJ;
    const int j  = vj - v * JJ;

    // ---- projection (uniform per block; compiler scalarizes to s_load) ----
    const float* P = proj + (size_t)(b * VV + v) * 12;
    const float* G = joints + (size_t)(b * JJ + j) * 3;
    const float X = G[0], Y = G[1], Z = G[2];
    const float px = P[0] * X + P[1] * Y + P[2]  * Z + P[3];
    const float py = P[4] * X + P[5] * Y + P[6]  * Z + P[7];
    const float pw = P[8] * X + P[9] * Y + P[10] * Z + P[11];
    const float jx = px / pw;
    const float jy = py / pw;

    // ---- per-thread gaussian factors, all in registers ----
    const int t  = threadIdx.x;
    const int w4 = t & 31;                      // float4 column (fixed)
    const int h0 = half * 64 + (t >> 5);        // starting row, +8 per k
    const float wbase = (float)(w4 * 4);

    float exr[4];
#pragma unroll
    for (int i = 0; i < 4; ++i) {
        float d = wbase + (float)i - jx;
        exr[i] = __expf(-0.5f * d * d);
    }
    float eyr[8];
#pragma unroll
    for (int k = 0; k < 8; ++k) {
        float d = (float)(h0 + k * 8) - jy;
        eyr[k] = __expf(-0.5f * d * d);
    }

    // ---- stream the half-slice: 2048 float4, 8/thread, coalesced, nt ----
    const f32x4* p4 = (const f32x4*)(pred + (size_t)bvj * SLICE) + half * 2048;
    float acc = 0.0f;
#pragma unroll
    for (int k = 0; k < 8; ++k) {
        const f32x4 p = __builtin_nontemporal_load(&p4[t + k * 256]);
        const float  e = eyr[k];
        float d0 = fmaf(-e, exr[0], p.x);
        float d1 = fmaf(-e, exr[1], p.y);
        float d2 = fmaf(-e, exr[2], p.z);
        float d3 = fmaf(-e, exr[3], p.w);
        acc = fmaf(d0, d0, acc);
        acc = fmaf(d1, d1, acc);
        acc = fmaf(d2, d2, acc);
        acc = fmaf(d3, d3, acc);
    }

    // ---- block reduction: wave64 shuffle then LDS across 4 waves ----
#pragma unroll
    for (int off = 32; off > 0; off >>= 1)
        acc += __shfl_down(acc, off, 64);
    __shared__ float wsum[4];
    if ((t & 63) == 0) wsum[t >> 6] = acc;
    __syncthreads();
    if (t == 0)
        partials[blk] = (wsum[0] + wsum[1] + wsum[2] + wsum[3]) * INV_NTOT;
}

// Kernel 2: deterministic single-block reduction of NBLK partials -> d_out[0].
// float4 loads: 1088 float4s = 1024 threads x1 + 64 threads x1 extra.
__global__ __launch_bounds__(1024)
void heatmap_mse_final(const float* __restrict__ partials, float* __restrict__ out)
{
    const int t = threadIdx.x;
    const float4* p4 = (const float4*)partials;   // NBLK/4 = 1088 float4
    float4 a = p4[t];
    float acc = a.x + a.y + a.z + a.w;
    if (t < 64) {
        float4 b = p4[1024 + t];
        acc += b.x + b.y + b.z + b.w;
    }
#pragma unroll
    for (int off = 32; off > 0; off >>= 1)
        acc += __shfl_down(acc, off, 64);
    __shared__ float wsum[16];
    if ((t & 63) == 0) wsum[t >> 6] = acc;
    __syncthreads();
    if (t == 0) {
        float total = 0.0f;
#pragma unroll
        for (int w = 0; w < 16; ++w) total += wsum[w];
        out[0] = total;                            // pre-scaled by 1/NTOT
    }
}

extern "C" void kernel_launch(void* const* d_in, const int* in_sizes, int n_in,
                              void* d_out, int out_size, void* d_ws, size_t ws_size,
                              hipStream_t stream)
{
    const float* pred   = (const float*)d_in[0];  // [B,V,J,H,W] f32
    const float* proj   = (const float*)d_in[1];  // [B,V,3,4]   f32
    const float* joints = (const float*)d_in[2];  // [B,J,3]     f32
    // d_in[3] = joints_3d_valid_batch (all ones; unused by the reference math)

    float* partials = (float*)d_ws;               // NBLK floats of scratch
    float* out      = (float*)d_out;

    heatmap_mse_partial<<<NBLK, 256, 0, stream>>>(pred, proj, joints, partials);
    heatmap_mse_final<<<1, 1024, 0, stream>>>(partials, out);
}

// Round 8
// 25.650 us; speedup vs baseline: 1.0187x; 1.0187x over previous
//
#include <hip/hip_runtime.h>
#include <hip/hip_bf16.h>

// Problem constants (match reference)
#define BB 32
#define VV 4
#define JJ 17
#define HH 128
#define WW 128

constexpr int   SLICE   = HH * WW;            // 16384 floats per (b,v,j)
constexpr int   NSLICE  = BB * VV * JJ;       // 2176 slices
constexpr int   NBLK    = NSLICE * 2;         // 4352 half-slice blocks
constexpr long long NTOT = (long long)NSLICE * SLICE; // 35,651,584
constexpr float INV_NTOT = 1.0f / (float)NTOT;

// Native clang vector for __builtin_nontemporal_load (HIP_vector_type invalid there)
typedef float f32x4 __attribute__((ext_vector_type(4)));

// Kernel 1: one block per HALF-slice (4352 blocks = exactly 17 per CU).
// LDS exp tables (256 expf/block, hidden by 8 resident blocks/CU), then
// stream 8 nt float4 loads/thread. gt = ey[h]*ex[w];
// partial = sum (pred - gt)^2, pre-scaled by 1/NTOT.
// [R7 lesson: in-register __expf variant (no LDS/barrier) was +0.4 us —
//  TLP already hides the prologue; keep the LDS form.]
__global__ __launch_bounds__(256)
void heatmap_mse_partial(const float* __restrict__ pred,
                         const float* __restrict__ proj,    // [B,V,3,4]
                         const float* __restrict__ joints,  // [B,J,3]
                         float* __restrict__ partials)      // [NBLK]
{
    const int blk  = blockIdx.x;
    const int bvj  = blk >> 1;        // slice index
    const int half = blk & 1;         // 0: rows 0..63, 1: rows 64..127
    const int b  = bvj / (VV * JJ);
    const int vj = bvj - b * (VV * JJ);
    const int v  = vj / JJ;
    const int j  = vj - v * JJ;

    // ---- projection (uniform per block; compiler scalarizes) ----
    const float* P = proj + (size_t)(b * VV + v) * 12;
    const float* G = joints + (size_t)(b * JJ + j) * 3;
    const float X = G[0], Y = G[1], Z = G[2];
    const float px = P[0] * X + P[1] * Y + P[2]  * Z + P[3];
    const float py = P[4] * X + P[5] * Y + P[6]  * Z + P[7];
    const float pw = P[8] * X + P[9] * Y + P[10] * Z + P[11];
    const float jx = px / pw;
    const float jy = py / pw;

    // ---- separable gaussian factors in LDS ----
    __shared__ __align__(16) float ex[WW];
    __shared__ __align__(16) float ey[HH];
    const int t = threadIdx.x;
    if (t < WW) {
        float d = (float)t - jx;
        ex[t] = expf(-0.5f * d * d);
    } else {
        int h = t - WW;
        float d = (float)h - jy;
        ey[h] = expf(-0.5f * d * d);
    }
    __syncthreads();

    // ---- loop-invariant ex fragment: one ds_read_b128 per thread ----
    const int w4 = t & 31;                      // float4 column, fixed across k
    const int h0 = half * 64 + (t >> 5);        // starting row, advances by 8
    const f32x4 x = *(const f32x4*)(&ex[w4 * 4]);

    // ---- stream the half-slice: 2048 float4, 8/thread, coalesced, nt ----
    const f32x4* p4 = (const f32x4*)(pred + (size_t)bvj * SLICE) + half * 2048;
    float acc = 0.0f;
#pragma unroll
    for (int k = 0; k < 8; ++k) {
        const f32x4 p = __builtin_nontemporal_load(&p4[t + k * 256]);
        const float  e = ey[h0 + k * 8];        // 2-value broadcast per wave
        float d0 = fmaf(-e, x.x, p.x);
        float d1 = fmaf(-e, x.y, p.y);
        float d2 = fmaf(-e, x.z, p.z);
        float d3 = fmaf(-e, x.w, p.w);
        acc = fmaf(d0, d0, acc);
        acc = fmaf(d1, d1, acc);
        acc = fmaf(d2, d2, acc);
        acc = fmaf(d3, d3, acc);
    }

    // ---- block reduction: wave64 shuffle then LDS across 4 waves ----
#pragma unroll
    for (int off = 32; off > 0; off >>= 1)
        acc += __shfl_down(acc, off, 64);
    __shared__ float wsum[4];
    if ((t & 63) == 0) wsum[t >> 6] = acc;
    __syncthreads();
    if (t == 0)
        partials[blk] = (wsum[0] + wsum[1] + wsum[2] + wsum[3]) * INV_NTOT;
}

// Kernel 2: deterministic single-block reduction of NBLK partials -> d_out[0].
// float4 loads: 1088 float4s = 1024 threads x1 + 64 threads x1 extra.
__global__ __launch_bounds__(1024)
void heatmap_mse_final(const float* __restrict__ partials, float* __restrict__ out)
{
    const int t = threadIdx.x;
    const float4* p4 = (const float4*)partials;   // NBLK/4 = 1088 float4
    float4 a = p4[t];
    float acc = a.x + a.y + a.z + a.w;
    if (t < 64) {
        float4 b = p4[1024 + t];
        acc += b.x + b.y + b.z + b.w;
    }
#pragma unroll
    for (int off = 32; off > 0; off >>= 1)
        acc += __shfl_down(acc, off, 64);
    __shared__ float wsum[16];
    if ((t & 63) == 0) wsum[t >> 6] = acc;
    __syncthreads();
    if (t == 0) {
        float total = 0.0f;
#pragma unroll
        for (int w = 0; w < 16; ++w) total += wsum[w];
        out[0] = total;                            // pre-scaled by 1/NTOT
    }
}

extern "C" void kernel_launch(void* const* d_in, const int* in_sizes, int n_in,
                              void* d_out, int out_size, void* d_ws, size_t ws_size,
                              hipStream_t stream)
{
    const float* pred   = (const float*)d_in[0];  // [B,V,J,H,W] f32
    const float* proj   = (const float*)d_in[1];  // [B,V,3,4]   f32
    const float* joints = (const float*)d_in[2];  // [B,J,3]     f32
    // d_in[3] = joints_3d_valid_batch (all ones; unused by the reference math)

    float* partials = (float*)d_ws;               // NBLK floats of scratch
    float* out      = (float*)d_out;

    heatmap_mse_partial<<<NBLK, 256, 0, stream>>>(pred, proj, joints, partials);
    heatmap_mse_final<<<1, 1024, 0, stream>>>(partials, out);
}